// Round 4
// baseline (5157.835 us; speedup 1.0000x reference)
//
#include <hip/hip_runtime.h>
#include <hip/hip_bf16.h>

#define H_ 1024
#define C_ 1536
#define B_ 256
#define T_ 128
#define IN_ 512
#define BH_ (B_*H_)

typedef __hip_bfloat16 bf16;
typedef __attribute__((ext_vector_type(8))) short short8;
typedef __attribute__((ext_vector_type(4))) float f32x4;
typedef unsigned int u32;

struct WPtrs { const float* W[10]; const float* wA; };
struct BPtrs { const float* b[10]; const float* bA[4]; };

__device__ __forceinline__ float sigmf(float x){ return 1.0f/(1.0f + __expf(-x)); }
__device__ __forceinline__ float tanhfast(float x){ return 1.0f - 2.0f/(__expf(2.0f*x) + 1.0f); }

__device__ __forceinline__ ushort bf16bits(float f){
    bf16 b = __float2bfloat16(f);
    return *reinterpret_cast<ushort*>(&b);
}
__device__ __forceinline__ float bf2f(ushort u){
    bf16 b = *reinterpret_cast<bf16*>(&u);
    return __bfloat162float(b);
}

// async global->LDS, 16B per lane; lds dest is wave-uniform base (+lane*16 by HW)
__device__ __forceinline__ void gload16(const void* g, void* l){
    __builtin_amdgcn_global_load_lds((const __attribute__((address_space(1))) u32*)g,
                                     (__attribute__((address_space(3))) u32*)l, 16, 0, 0);
}

// ---- weight transpose+convert: src fp32 [K][H] -> dst bf16 [H][K]
__global__ void transpose_w(WPtrs wp, ushort* __restrict__ Wt, ushort* __restrict__ wAt)
{
    int g = blockIdx.z;
    int K = (g==10) ? H_ : C_;
    int k0 = blockIdx.x*32, n0 = blockIdx.y*32;
    if (k0 >= K) return;
    const float* src = (g==10) ? wp.wA : wp.W[g];
    __shared__ float tile[32][33];
    int tx = threadIdx.x, ty = threadIdx.y;
    #pragma unroll
    for (int i=0;i<32;i+=8)
        tile[ty+i][tx] = src[(size_t)(k0+ty+i)*H_ + n0 + tx];
    __syncthreads();
    ushort* dst = (g==10) ? wAt : (Wt + (size_t)g*H_*C_);
    #pragma unroll
    for (int i=0;i<32;i+=8)
        dst[(size_t)(n0+ty+i)*K + k0 + tx] = bf16bits(tile[tx][ty+i]);
}

// ---- x fp32 -> bf16, all 4 factor arrays
__global__ void convert_x(const float* __restrict__ xY, const float* __restrict__ xI,
                          const float* __restrict__ xP, const float* __restrict__ xN,
                          ushort* __restrict__ xb)
{
    size_t idx = (size_t)blockIdx.x*blockDim.x + threadIdx.x;
    size_t base = idx*4;
    size_t a = base >> 24;
    size_t off = base & ((size_t)(1u<<24)-1);
    const float* s = (a==0)?xY:(a==1)?xI:(a==2)?xP:xN;
    float4 v = *(const float4*)(s + off);
    ushort4 o;
    o.x = bf16bits(v.x); o.y = bf16bits(v.y); o.z = bf16bits(v.z); o.w = bf16bits(v.w);
    *(ushort4*)(xb + base) = o;
}

// ---- precompute Xp[t][g][b][n] = x_g[b,t,:] @ W_g[IN-part]  (bf16 out)
// (opportunistic; only if ws_size large enough)
__global__ __launch_bounds__(256) void xp_gemm(const ushort* __restrict__ Wt,
                                               const ushort* __restrict__ xb,
                                               ushort* __restrict__ Xp)
{
    int bid = blockIdx.x;
    int xcd = bid & 7, lid = bid >> 3;
    int ntile = xcd*20 + (lid >> 9);
    int mtile = lid & 511;
    int g = ntile >> 4;
    int n0g = (ntile & 15)*64;
    int tq = mtile >> 2;
    int b0 = (mtile & 3)*64;
    int xs = (g==3)?1:(g==4)?2:(g==5)?3:0;
    const ushort* xsrc = xb + (size_t)xs*((size_t)B_*T_*IN_);
    const ushort* Bbase = Wt + (size_t)g*H_*C_ + 1024;

    __shared__ ushort As[64][64];
    __shared__ ushort Bs[64][64];
    int tid = threadIdx.x;
    int wid = tid>>6, lane = tid&63;
    int wr = wid>>1, wc = wid&1;

    f32x4 acc[2][2] = {};
    for (int k0=0; k0<IN_; k0+=64){
        #pragma unroll
        for (int it=0; it<2; ++it){
            int cid = it*256 + tid;
            int row = cid>>3, kc = cid&7;
            int kcs = kc ^ (row&7);
            gload16(xsrc + ((size_t)(b0+row)*T_ + tq)*IN_ + k0 + kcs*8,
                    (ushort*)As + (size_t)(it*256 + wid*64)*8);
        }
        #pragma unroll
        for (int it=0; it<2; ++it){
            int cid = it*256 + tid;
            int row = cid>>3, kc = cid&7;
            int kcs = kc ^ (row&7);
            gload16(Bbase + (size_t)(n0g+row)*C_ + k0 + kcs*8,
                    (ushort*)Bs + (size_t)(it*256 + wid*64)*8);
        }
        __syncthreads();
        #pragma unroll
        for (int kk=0; kk<2; ++kk){
            short8 af[2], bfr[2];
            #pragma unroll
            for (int mr=0;mr<2;++mr){
                int r = wr*32 + mr*16 + (lane&15);
                int j = (kk*4 + (lane>>4)) ^ (r&7);
                af[mr] = *(const short8*)((ushort*)As + r*64 + j*8);
            }
            #pragma unroll
            for (int nr=0;nr<2;++nr){
                int r = wc*32 + nr*16 + (lane&15);
                int j = (kk*4 + (lane>>4)) ^ (r&7);
                bfr[nr] = *(const short8*)((ushort*)Bs + r*64 + j*8);
            }
            #pragma unroll
            for (int mr=0;mr<2;++mr)
                #pragma unroll
                for (int nr=0;nr<2;++nr)
                    acc[mr][nr] = __builtin_amdgcn_mfma_f32_16x16x32_bf16(af[mr], bfr[nr], acc[mr][nr], 0,0,0);
        }
        __syncthreads();
    }
    ushort* Xg = Xp + (((size_t)tq*10 + g)*B_ + b0)*H_ + n0g;
    #pragma unroll
    for (int mr=0;mr<2;++mr){
        #pragma unroll
        for (int nr=0;nr<2;++nr){
            int col = wc*32 + nr*16 + (lane&15);
            #pragma unroll
            for (int r=0;r<4;++r){
                int row = wr*32 + mr*16 + (lane>>4)*4 + r;
                Xg[(size_t)row*H_ + col] = bf16bits(acc[mr][nr][r]);
            }
        }
    }
}

// ---- per-step GEMM: 176 blocks = 88 n-tiles(128) x 2 m-tiles(128).
// 4 waves (2x2), each wave computes a 64x64 output tile (acc[4][4]).
// Double-buffered LDS, single barrier per K-iter.
template<bool XP>
__global__ __launch_bounds__(256) void gemm_step(
    const ushort* __restrict__ Wt, const ushort* __restrict__ wAt,
    const ushort* __restrict__ xb, const ushort* __restrict__ hb,
    const ushort* __restrict__ cbuf, const ushort* __restrict__ Xp,
    float* __restrict__ P, int t)
{
    int bid = blockIdx.x;
    int xcd = bid & 7, lid = bid >> 3;     // lid in [0,22)
    int ntile = xcd*11 + (lid >> 1);       // [0,88)
    int mtile = lid & 1;
    int g = ntile >> 3;                    // 128-wide tiles: 8 per gate
    int n0g = (ntile & 7)*128;
    int m0 = mtile*128;
    bool isA = (g==10);
    const ushort* Bbase = isA ? wAt : (Wt + (size_t)g*H_*C_);
    size_t Bstride = isA ? 1024 : 1536;
    int K = XP ? 1024 : (isA ? 1024 : 1536);
    int xs = (g==3)?1:(g==4)?2:(g==5)?3:0;
    const ushort* xsrc = xb + (size_t)xs*((size_t)B_*T_*IN_);
    const ushort* Ah = isA ? cbuf : hb;

    __shared__ ushort As[2][128*64];
    __shared__ ushort Bs[2][128*64];
    int tid = threadIdx.x;
    int wid = tid>>6, lane = tid&63;
    int wr = wid>>1, wc = wid&1;

    auto stage = [&](int buf, int k0){
        ushort* la = As[buf];
        ushort* lb = Bs[buf];
        #pragma unroll
        for (int it=0; it<4; ++it){
            int cid = it*256 + tid;
            int row = cid>>3, kc = cid&7;
            int kcs = kc ^ (row&7);
            int k = k0 + kcs*8;
            const ushort* src;
            if (XP || isA || k < 1024) src = Ah + (size_t)(m0+row)*H_ + k;
            else                       src = xsrc + ((size_t)(m0+row)*T_ + t)*IN_ + (k-1024);
            gload16(src, la + (size_t)(it*256 + wid*64)*8);
        }
        #pragma unroll
        for (int it=0; it<4; ++it){
            int cid = it*256 + tid;
            int row = cid>>3, kc = cid&7;
            int kcs = kc ^ (row&7);
            gload16(Bbase + (size_t)(n0g+row)*Bstride + k0 + kcs*8,
                    lb + (size_t)(it*256 + wid*64)*8);
        }
    };

    f32x4 acc[4][4] = {};
    stage(0, 0);

    if (XP && !isA){
        const ushort* Xg = Xp + (((size_t)t*10 + g)*B_ + m0)*H_ + n0g;
        #pragma unroll
        for (int mr=0;mr<4;++mr)
            #pragma unroll
            for (int nr=0;nr<4;++nr){
                int col = wc*64 + nr*16 + (lane&15);
                #pragma unroll
                for (int r=0;r<4;++r){
                    int row = wr*64 + mr*16 + (lane>>4)*4 + r;
                    acc[mr][nr][r] = bf2f(Xg[(size_t)row*H_ + col]);
                }
            }
    }
    __syncthreads();                 // buf0 ready

    int nIter = K >> 6;
    for (int i=0; i<nIter; ++i){
        int cur = i & 1;
        if (i+1 < nIter) stage(cur^1, (i+1)<<6);
        ushort* la = As[cur];
        ushort* lb = Bs[cur];
        #pragma unroll
        for (int kk=0; kk<2; ++kk){
            short8 af[4], bfr[4];
            #pragma unroll
            for (int mr=0;mr<4;++mr){
                int r = wr*64 + mr*16 + (lane&15);
                int j = (kk*4 + (lane>>4)) ^ (r&7);
                af[mr] = *(const short8*)(la + r*64 + j*8);
            }
            #pragma unroll
            for (int nr=0;nr<4;++nr){
                int r = wc*64 + nr*16 + (lane&15);
                int j = (kk*4 + (lane>>4)) ^ (r&7);
                bfr[nr] = *(const short8*)(lb + r*64 + j*8);
            }
            #pragma unroll
            for (int mr=0;mr<4;++mr)
                #pragma unroll
                for (int nr=0;nr<4;++nr)
                    acc[mr][nr] = __builtin_amdgcn_mfma_f32_16x16x32_bf16(af[mr], bfr[nr], acc[mr][nr], 0,0,0);
        }
        __syncthreads();
    }

    float* Pg = P + (size_t)g*BH_;
    #pragma unroll
    for (int mr=0;mr<4;++mr){
        #pragma unroll
        for (int nr=0;nr<4;++nr){
            int col = n0g + wc*64 + nr*16 + (lane&15);
            #pragma unroll
            for (int r=0;r<4;++r){
                int rowg = m0 + wr*64 + mr*16 + (lane>>4)*4 + r;
                Pg[(size_t)rowg*H_ + col] = acc[mr][nr][r];
            }
        }
    }
}

// ---- per-row: gates -> scores -> Z -> softmax cols 0..3 -> c,h update
__global__ __launch_bounds__(1024) void step_update(
    const float* __restrict__ P, BPtrs bp,
    float* __restrict__ c, ushort* __restrict__ hb, ushort* __restrict__ cbuf,
    float* __restrict__ out, int t)
{
    int b = blockIdx.x;
    int j = threadIdx.x;
    int wid = j>>6, lane = j&63;
    const float* Pb = P + (size_t)b*H_;

    float fv = sigmf(Pb[(size_t)0*BH_ + j] + bp.b[0][j]);
    float ov = sigmf(Pb[(size_t)1*BH_ + j] + bp.b[1][j]);
    float lY = tanhfast(Pb[(size_t)2*BH_ + j] + bp.b[2][j]) * sigmf(Pb[(size_t)6*BH_ + j] + bp.b[6][j]);
    float lI = tanhfast(Pb[(size_t)3*BH_ + j] + bp.b[3][j]) * sigmf(Pb[(size_t)7*BH_ + j] + bp.b[7][j]);
    float lP = tanhfast(Pb[(size_t)4*BH_ + j] + bp.b[4][j]) * sigmf(Pb[(size_t)8*BH_ + j] + bp.b[8][j]);
    float lN = tanhfast(Pb[(size_t)5*BH_ + j] + bp.b[5][j]) * sigmf(Pb[(size_t)9*BH_ + j] + bp.b[9][j]);
    float cw = Pb[(size_t)10*BH_ + j];

    float v0=lY*cw, v1=lI*cw, v2=lP*cw, v3=lN*cw;
    #pragma unroll
    for (int d=32; d>=1; d>>=1){
        v0 += __shfl_down(v0,d); v1 += __shfl_down(v1,d);
        v2 += __shfl_down(v2,d); v3 += __shfl_down(v3,d);
    }
    __shared__ float red[16][4];
    if (lane==0){ red[wid][0]=v0; red[wid][1]=v1; red[wid][2]=v2; red[wid][3]=v3; }
    __syncthreads();
    float sY=0, sI=0, sP=0, sN=0;
    #pragma unroll
    for (int w=0; w<16; ++w){
        sY += red[w][0]; sI += red[w][1]; sP += red[w][2]; sN += red[w][3];
    }

    float zp = __expf(tanhfast(sY + bp.bA[0][j]))
             + __expf(tanhfast(sI + bp.bA[1][j]))
             + __expf(tanhfast(sP + bp.bA[2][j]))
             + __expf(tanhfast(sN + bp.bA[3][j]));
    #pragma unroll
    for (int d=32; d>=1; d>>=1) zp += __shfl_down(zp,d);
    __shared__ float zred[16];
    if (lane==0) zred[wid] = zp;
    __syncthreads();
    float Z = 0;
    #pragma unroll
    for (int w=0; w<16; ++w) Z += zred[w];
    float Zi = 1.0f / Z;
    float a0 = __expf(tanhfast(sY + bp.bA[0][0]))*Zi;
    float a1 = __expf(tanhfast(sY + bp.bA[0][1]))*Zi;
    float a2 = __expf(tanhfast(sY + bp.bA[0][2]))*Zi;
    float a3 = __expf(tanhfast(sY + bp.bA[0][3]))*Zi;

    float lT = a0*lY + a1*lI + a2*lP + a3*lN;
    float cn = c[(size_t)b*H_ + j]*fv + lT;
    c[(size_t)b*H_ + j] = cn;
    cbuf[(size_t)b*H_ + j] = bf16bits(cn);
    float hn = tanhfast(cn)*ov;
    hb[(size_t)b*H_ + j] = bf16bits(hn);
    out[((size_t)b*T_ + t)*H_ + j] = hn;
}

extern "C" void kernel_launch(void* const* d_in, const int* in_sizes, int n_in,
                              void* d_out, int out_size, void* d_ws, size_t ws_size,
                              hipStream_t stream)
{
    WPtrs wp; BPtrs bp;
    for (int i=0;i<10;++i){ wp.W[i] = (const float*)d_in[2*i]; bp.b[i] = (const float*)d_in[2*i+1]; }
    wp.wA = (const float*)d_in[20];
    for (int i=0;i<4;++i) bp.bA[i] = (const float*)d_in[21+i];
    const float* xY = (const float*)d_in[25];
    const float* xI = (const float*)d_in[26];
    const float* xP = (const float*)d_in[27];
    const float* xN = (const float*)d_in[28];

    char* w = (char*)d_ws;
    size_t off = 0;
    ushort* Wt  = (ushort*)(w+off); off += (size_t)10*H_*C_*2;
    ushort* wAt = (ushort*)(w+off); off += (size_t)H_*H_*2;
    ushort* xb  = (ushort*)(w+off); off += (size_t)4*B_*T_*IN_*2;
    float*  P   = (float*)(w+off);  off += (size_t)11*BH_*4;
    float*  c   = (float*)(w+off);  off += (size_t)BH_*4;
    ushort* hb  = (ushort*)(w+off); off += (size_t)BH_*2;
    ushort* cbuf= (ushort*)(w+off); off += (size_t)BH_*2;
    ushort* Xp  = (ushort*)(w+off);
    size_t need_xp = off + (size_t)T_*10*B_*H_*2;
    bool xp_ok = (ws_size >= need_xp);

    hipMemsetAsync(c, 0, (size_t)BH_*8, stream);

    transpose_w<<<dim3(C_/32, H_/32, 11), dim3(32,8), 0, stream>>>(wp, Wt, wAt);
    convert_x<<<(4u*B_*T_*IN_/4)/256, 256, 0, stream>>>(xY,xI,xP,xN, xb);

    float* out = (float*)d_out;
    if (xp_ok){
        xp_gemm<<<81920, 256, 0, stream>>>(Wt, xb, Xp);
        for (int t=0;t<T_;++t){
            gemm_step<true><<<176, 256, 0, stream>>>(Wt, wAt, xb, hb, cbuf, Xp, P, t);
            step_update<<<B_, 1024, 0, stream>>>(P, bp, c, hb, cbuf, out, t);
        }
    } else {
        for (int t=0;t<T_;++t){
            gemm_step<false><<<176, 256, 0, stream>>>(Wt, wAt, xb, hb, cbuf, Xp, P, t);
            step_update<<<B_, 1024, 0, stream>>>(P, bp, c, hb, cbuf, out, t);
        }
    }
}

// Round 5
// 3601.119 us; speedup vs baseline: 1.4323x; 1.4323x over previous
//
#include <hip/hip_runtime.h>
#include <hip/hip_bf16.h>

#define H_ 1024
#define C_ 1536
#define B_ 256
#define T_ 128
#define IN_ 512
#define BH_ (B_*H_)

typedef __hip_bfloat16 bf16;
typedef __attribute__((ext_vector_type(8))) short short8;
typedef __attribute__((ext_vector_type(4))) float f32x4;
typedef unsigned int u32;

struct WPtrs { const float* W[10]; const float* wA; };
struct BPtrs { const float* b[10]; const float* bA[4]; };

__device__ __forceinline__ float sigmf(float x){ return 1.0f/(1.0f + __expf(-x)); }
__device__ __forceinline__ float tanhfast(float x){ return 1.0f - 2.0f/(__expf(2.0f*x) + 1.0f); }

__device__ __forceinline__ ushort bf16bits(float f){
    bf16 b = __float2bfloat16(f);
    return *reinterpret_cast<ushort*>(&b);
}
__device__ __forceinline__ float bf2f(ushort u){
    bf16 b = *reinterpret_cast<bf16*>(&u);
    return __bfloat162float(b);
}

// async global->LDS, 16B per lane; lds dest is wave-uniform base (+lane*16 by HW)
__device__ __forceinline__ void gload16(const void* g, void* l){
    __builtin_amdgcn_global_load_lds((const __attribute__((address_space(1))) u32*)g,
                                     (__attribute__((address_space(3))) u32*)l, 16, 0, 0);
}

// ---- weight transpose+convert: src fp32 [K][H] -> dst bf16 [H][K]
__global__ void transpose_w(WPtrs wp, ushort* __restrict__ Wt, ushort* __restrict__ wAt)
{
    int g = blockIdx.z;
    int K = (g==10) ? H_ : C_;
    int k0 = blockIdx.x*32, n0 = blockIdx.y*32;
    if (k0 >= K) return;
    const float* src = (g==10) ? wp.wA : wp.W[g];
    __shared__ float tile[32][33];
    int tx = threadIdx.x, ty = threadIdx.y;
    #pragma unroll
    for (int i=0;i<32;i+=8)
        tile[ty+i][tx] = src[(size_t)(k0+ty+i)*H_ + n0 + tx];
    __syncthreads();
    ushort* dst = (g==10) ? wAt : (Wt + (size_t)g*H_*C_);
    #pragma unroll
    for (int i=0;i<32;i+=8)
        dst[(size_t)(n0+ty+i)*K + k0 + tx] = bf16bits(tile[tx][ty+i]);
}

// ---- x fp32 -> bf16, all 4 factor arrays
__global__ void convert_x(const float* __restrict__ xY, const float* __restrict__ xI,
                          const float* __restrict__ xP, const float* __restrict__ xN,
                          ushort* __restrict__ xb)
{
    size_t idx = (size_t)blockIdx.x*blockDim.x + threadIdx.x;
    size_t base = idx*4;
    size_t a = base >> 24;
    size_t off = base & ((size_t)(1u<<24)-1);
    const float* s = (a==0)?xY:(a==1)?xI:(a==2)?xP:xN;
    float4 v = *(const float4*)(s + off);
    ushort4 o;
    o.x = bf16bits(v.x); o.y = bf16bits(v.y); o.z = bf16bits(v.z); o.w = bf16bits(v.w);
    *(ushort4*)(xb + base) = o;
}

// ---- precompute Xp[t][g][b][n] = x_g[b,t,:] @ W_g[IN-part]  (bf16 out)
// (opportunistic; only if ws_size large enough)
__global__ __launch_bounds__(256) void xp_gemm(const ushort* __restrict__ Wt,
                                               const ushort* __restrict__ xb,
                                               ushort* __restrict__ Xp)
{
    int bid = blockIdx.x;
    int xcd = bid & 7, lid = bid >> 3;
    int ntile = xcd*20 + (lid >> 9);
    int mtile = lid & 511;
    int g = ntile >> 4;
    int n0g = (ntile & 15)*64;
    int tq = mtile >> 2;
    int b0 = (mtile & 3)*64;
    int xs = (g==3)?1:(g==4)?2:(g==5)?3:0;
    const ushort* xsrc = xb + (size_t)xs*((size_t)B_*T_*IN_);
    const ushort* Bbase = Wt + (size_t)g*H_*C_ + 1024;

    __shared__ ushort As[64][64];
    __shared__ ushort Bs[64][64];
    int tid = threadIdx.x;
    int wid = tid>>6, lane = tid&63;
    int wr = wid>>1, wc = wid&1;

    f32x4 acc[2][2] = {};
    for (int k0=0; k0<IN_; k0+=64){
        #pragma unroll
        for (int it=0; it<2; ++it){
            int cid = it*256 + tid;
            int row = cid>>3, kc = cid&7;
            int kcs = kc ^ (row&7);
            gload16(xsrc + ((size_t)(b0+row)*T_ + tq)*IN_ + k0 + kcs*8,
                    (ushort*)As + (size_t)(it*256 + wid*64)*8);
        }
        #pragma unroll
        for (int it=0; it<2; ++it){
            int cid = it*256 + tid;
            int row = cid>>3, kc = cid&7;
            int kcs = kc ^ (row&7);
            gload16(Bbase + (size_t)(n0g+row)*C_ + k0 + kcs*8,
                    (ushort*)Bs + (size_t)(it*256 + wid*64)*8);
        }
        __syncthreads();
        #pragma unroll
        for (int kk=0; kk<2; ++kk){
            short8 af[2], bfr[2];
            #pragma unroll
            for (int mr=0;mr<2;++mr){
                int r = wr*32 + mr*16 + (lane&15);
                int j = (kk*4 + (lane>>4)) ^ (r&7);
                af[mr] = *(const short8*)((ushort*)As + r*64 + j*8);
            }
            #pragma unroll
            for (int nr=0;nr<2;++nr){
                int r = wc*32 + nr*16 + (lane&15);
                int j = (kk*4 + (lane>>4)) ^ (r&7);
                bfr[nr] = *(const short8*)((ushort*)Bs + r*64 + j*8);
            }
            #pragma unroll
            for (int mr=0;mr<2;++mr)
                #pragma unroll
                for (int nr=0;nr<2;++nr)
                    acc[mr][nr] = __builtin_amdgcn_mfma_f32_16x16x32_bf16(af[mr], bfr[nr], acc[mr][nr], 0,0,0);
        }
        __syncthreads();
    }
    ushort* Xg = Xp + (((size_t)tq*10 + g)*B_ + b0)*H_ + n0g;
    #pragma unroll
    for (int mr=0;mr<2;++mr){
        #pragma unroll
        for (int nr=0;nr<2;++nr){
            int col = wc*32 + nr*16 + (lane&15);
            #pragma unroll
            for (int r=0;r<4;++r){
                int row = wr*32 + mr*16 + (lane>>4)*4 + r;
                Xg[(size_t)row*H_ + col] = bf16bits(acc[mr][nr][r]);
            }
        }
    }
}

// ---- per-step GEMM, split-K=2.
// 704 blocks = 8 XCD x 11 n-tiles(128) x 4 m-tiles(64) x 2 k-splits.
// 128 threads = 2 waves; each wave computes 64(m) x 64(n) (acc[4][4]).
// Double-buffered LDS (48KB), single barrier per K-iter.
// Partial sums written to P[split][gate][b][n]; update kernel adds the two.
template<bool XP>
__global__ __launch_bounds__(128, 2) void gemm_step(
    const ushort* __restrict__ Wt, const ushort* __restrict__ wAt,
    const ushort* __restrict__ xb, const ushort* __restrict__ hb,
    const ushort* __restrict__ cbuf, const ushort* __restrict__ Xp,
    float* __restrict__ P, int t)
{
    int bid = blockIdx.x;
    int xcd = bid & 7, lid = bid >> 3;     // lid in [0,88)
    int ntile = xcd*11 + (lid >> 3);       // [0,88)
    int rem = lid & 7;
    int mtile = rem >> 1;                  // [0,4)
    int split = rem & 1;                   // [0,2)
    int nglob0 = ntile*128;
    int g = nglob0 >> 10;
    int n0g = nglob0 & 1023;
    int m0 = mtile*64;
    bool isA = (g==10);
    const ushort* Bbase = isA ? wAt : (Wt + (size_t)g*H_*C_);
    size_t Bstride = isA ? 1024 : 1536;
    int kStart, kEnd;
    if (XP || isA){ kStart = split*512; kEnd = kStart + 512; }
    else          { kStart = split*768; kEnd = kStart + 768; }
    int xs = (g==3)?1:(g==4)?2:(g==5)?3:0;
    const ushort* xsrc = xb + (size_t)xs*((size_t)B_*T_*IN_);
    const ushort* Ah = isA ? cbuf : hb;

    __shared__ ushort As[2][64*64];
    __shared__ ushort Bs[2][128*64];
    int tid = threadIdx.x;
    int wid = tid>>6, lane = tid&63;

    auto stage = [&](int buf, int k0){
        ushort* la = As[buf];
        ushort* lb = Bs[buf];
        #pragma unroll
        for (int it=0; it<4; ++it){        // A: 64 rows x 8 kc = 512 slots
            int cid = it*128 + tid;
            int row = cid>>3, kc = cid&7;
            int kcs = kc ^ (row&7);
            int k = k0 + kcs*8;
            const ushort* src;
            if (XP || isA || k < 1024) src = Ah + (size_t)(m0+row)*H_ + k;
            else                       src = xsrc + ((size_t)(m0+row)*T_ + t)*IN_ + (k-1024);
            gload16(src, la + (size_t)(it*128 + wid*64)*8);
        }
        #pragma unroll
        for (int it=0; it<8; ++it){        // B: 128 rows x 8 kc = 1024 slots
            int cid = it*128 + tid;
            int row = cid>>3, kc = cid&7;
            int kcs = kc ^ (row&7);
            gload16(Bbase + (size_t)(n0g+row)*Bstride + k0 + kcs*8,
                    lb + (size_t)(it*128 + wid*64)*8);
        }
    };

    f32x4 acc[4][4] = {};
    stage(0, kStart);

    if (XP && !isA && split==0){
        const ushort* Xg = Xp + (((size_t)t*10 + g)*B_ + m0)*H_ + n0g;
        #pragma unroll
        for (int mr=0;mr<4;++mr)
            #pragma unroll
            for (int nr=0;nr<4;++nr){
                int col = wid*64 + nr*16 + (lane&15);
                #pragma unroll
                for (int r=0;r<4;++r){
                    int row = mr*16 + (lane>>4)*4 + r;
                    acc[mr][nr][r] = bf2f(Xg[(size_t)row*H_ + col]);
                }
            }
    }
    __syncthreads();                 // buf0 ready

    int nIter = (kEnd - kStart) >> 6;
    for (int i=0; i<nIter; ++i){
        int cur = i & 1;
        if (i+1 < nIter) stage(cur^1, kStart + ((i+1)<<6));
        ushort* la = As[cur];
        ushort* lb = Bs[cur];
        #pragma unroll
        for (int kk=0; kk<2; ++kk){
            short8 af[4], bfr[4];
            #pragma unroll
            for (int mr=0;mr<4;++mr){
                int r = mr*16 + (lane&15);
                int j = (kk*4 + (lane>>4)) ^ (r&7);
                af[mr] = *(const short8*)(la + r*64 + j*8);
            }
            #pragma unroll
            for (int nr=0;nr<4;++nr){
                int r = wid*64 + nr*16 + (lane&15);
                int j = (kk*4 + (lane>>4)) ^ (r&7);
                bfr[nr] = *(const short8*)(lb + r*64 + j*8);
            }
            #pragma unroll
            for (int mr=0;mr<4;++mr)
                #pragma unroll
                for (int nr=0;nr<4;++nr)
                    acc[mr][nr] = __builtin_amdgcn_mfma_f32_16x16x32_bf16(af[mr], bfr[nr], acc[mr][nr], 0,0,0);
        }
        __syncthreads();
    }

    float* Pg = P + ((size_t)split*11 + g)*BH_;
    #pragma unroll
    for (int mr=0;mr<4;++mr){
        #pragma unroll
        for (int nr=0;nr<4;++nr){
            int col = n0g + wid*64 + nr*16 + (lane&15);
            #pragma unroll
            for (int r=0;r<4;++r){
                int rowg = m0 + mr*16 + (lane>>4)*4 + r;
                Pg[(size_t)rowg*H_ + col] = acc[mr][nr][r];
            }
        }
    }
}

// ---- per-row: sum split-K partials -> gates -> scores -> Z -> softmax -> c,h
__global__ __launch_bounds__(1024) void step_update(
    const float* __restrict__ P, BPtrs bp,
    float* __restrict__ c, ushort* __restrict__ hb, ushort* __restrict__ cbuf,
    float* __restrict__ out, int t)
{
    int b = blockIdx.x;
    int j = threadIdx.x;
    int wid = j>>6, lane = j&63;
    const float* Pb = P + (size_t)b*H_;

    auto gp = [&](int g){
        return Pb[(size_t)g*BH_ + j] + Pb[(size_t)(11+g)*BH_ + j];
    };

    float fv = sigmf(gp(0) + bp.b[0][j]);
    float ov = sigmf(gp(1) + bp.b[1][j]);
    float lY = tanhfast(gp(2) + bp.b[2][j]) * sigmf(gp(6) + bp.b[6][j]);
    float lI = tanhfast(gp(3) + bp.b[3][j]) * sigmf(gp(7) + bp.b[7][j]);
    float lP = tanhfast(gp(4) + bp.b[4][j]) * sigmf(gp(8) + bp.b[8][j]);
    float lN = tanhfast(gp(5) + bp.b[5][j]) * sigmf(gp(9) + bp.b[9][j]);
    float cw = gp(10);

    float v0=lY*cw, v1=lI*cw, v2=lP*cw, v3=lN*cw;
    #pragma unroll
    for (int d=32; d>=1; d>>=1){
        v0 += __shfl_down(v0,d); v1 += __shfl_down(v1,d);
        v2 += __shfl_down(v2,d); v3 += __shfl_down(v3,d);
    }
    __shared__ float red[16][4];
    if (lane==0){ red[wid][0]=v0; red[wid][1]=v1; red[wid][2]=v2; red[wid][3]=v3; }
    __syncthreads();
    float sY=0, sI=0, sP=0, sN=0;
    #pragma unroll
    for (int w=0; w<16; ++w){
        sY += red[w][0]; sI += red[w][1]; sP += red[w][2]; sN += red[w][3];
    }

    float zp = __expf(tanhfast(sY + bp.bA[0][j]))
             + __expf(tanhfast(sI + bp.bA[1][j]))
             + __expf(tanhfast(sP + bp.bA[2][j]))
             + __expf(tanhfast(sN + bp.bA[3][j]));
    #pragma unroll
    for (int d=32; d>=1; d>>=1) zp += __shfl_down(zp,d);
    __shared__ float zred[16];
    if (lane==0) zred[wid] = zp;
    __syncthreads();
    float Z = 0;
    #pragma unroll
    for (int w=0; w<16; ++w) Z += zred[w];
    float Zi = 1.0f / Z;
    float a0 = __expf(tanhfast(sY + bp.bA[0][0]))*Zi;
    float a1 = __expf(tanhfast(sY + bp.bA[0][1]))*Zi;
    float a2 = __expf(tanhfast(sY + bp.bA[0][2]))*Zi;
    float a3 = __expf(tanhfast(sY + bp.bA[0][3]))*Zi;

    float lT = a0*lY + a1*lI + a2*lP + a3*lN;
    float cn = c[(size_t)b*H_ + j]*fv + lT;
    c[(size_t)b*H_ + j] = cn;
    cbuf[(size_t)b*H_ + j] = bf16bits(cn);
    float hn = tanhfast(cn)*ov;
    hb[(size_t)b*H_ + j] = bf16bits(hn);
    out[((size_t)b*T_ + t)*H_ + j] = hn;
}

extern "C" void kernel_launch(void* const* d_in, const int* in_sizes, int n_in,
                              void* d_out, int out_size, void* d_ws, size_t ws_size,
                              hipStream_t stream)
{
    WPtrs wp; BPtrs bp;
    for (int i=0;i<10;++i){ wp.W[i] = (const float*)d_in[2*i]; bp.b[i] = (const float*)d_in[2*i+1]; }
    wp.wA = (const float*)d_in[20];
    for (int i=0;i<4;++i) bp.bA[i] = (const float*)d_in[21+i];
    const float* xY = (const float*)d_in[25];
    const float* xI = (const float*)d_in[26];
    const float* xP = (const float*)d_in[27];
    const float* xN = (const float*)d_in[28];

    char* w = (char*)d_ws;
    size_t off = 0;
    ushort* Wt  = (ushort*)(w+off); off += (size_t)10*H_*C_*2;        // 31.46 MB
    ushort* wAt = (ushort*)(w+off); off += (size_t)H_*H_*2;           // 2 MB
    ushort* xb  = (ushort*)(w+off); off += (size_t)4*B_*T_*IN_*2;     // 134.2 MB
    float*  P   = (float*)(w+off);  off += (size_t)22*BH_*4;          // 23 MB (2 split-K partials)
    float*  c   = (float*)(w+off);  off += (size_t)BH_*4;
    ushort* hb  = (ushort*)(w+off); off += (size_t)BH_*2;
    ushort* cbuf= (ushort*)(w+off); off += (size_t)BH_*2;
    ushort* Xp  = (ushort*)(w+off);
    size_t need_xp = off + (size_t)T_*10*B_*H_*2;
    bool xp_ok = (ws_size >= need_xp);

    hipMemsetAsync(c, 0, (size_t)BH_*8, stream);

    transpose_w<<<dim3(C_/32, H_/32, 11), dim3(32,8), 0, stream>>>(wp, Wt, wAt);
    convert_x<<<(4u*B_*T_*IN_/4)/256, 256, 0, stream>>>(xY,xI,xP,xN, xb);

    float* out = (float*)d_out;
    if (xp_ok){
        xp_gemm<<<81920, 256, 0, stream>>>(Wt, xb, Xp);
        for (int t=0;t<T_;++t){
            gemm_step<true><<<704, 128, 0, stream>>>(Wt, wAt, xb, hb, cbuf, Xp, P, t);
            step_update<<<B_, 1024, 0, stream>>>(P, bp, c, hb, cbuf, out, t);
        }
    } else {
        for (int t=0;t<T_;++t){
            gemm_step<false><<<704, 128, 0, stream>>>(Wt, wAt, xb, hb, cbuf, Xp, P, t);
            step_update<<<B_, 1024, 0, stream>>>(P, bp, c, hb, cbuf, out, t);
        }
    }
}